// Round 3
// baseline (13908.952 us; speedup 1.0000x reference)
//
#include <hip/hip_runtime.h>
#include <hip/hip_cooperative_groups.h>
#include <cmath>

namespace cg = cooperative_groups;

namespace {

constexpr int Dm  = 512;
constexpr int Bn  = 32;
constexpr int Lq  = 16;
constexpr int V1  = 8193;
constexpr int DFF = 2048;
constexpr int NL  = 2;
constexpr int NB  = 256;   // blocks (1/CU guaranteed co-resident)
constexpr int NT  = 256;   // threads/block (4 waves)

struct Args {
  const int*   meanings;
  const float* emb_table;
  const float* v2e_w;
  const float* e2v_w;  const float* e2v_b;
  const float* sa_qkv_w; const float* sa_qkv_b;
  const float* sa_out_w; const float* sa_out_b;
  const float* ca_qkv_w; const float* ca_qkv_b;
  const float* ca_out_w; const float* ca_out_b;
  const float* ffn_w1; const float* ffn_b1;
  const float* ffn_w2; const float* ffn_b2;
  const float* ln1_g; const float* ln1_b;
  const float* ln2_g; const float* ln2_b;
  const float* ln3_g; const float* ln3_b;
  float* outToks;   // [16,32] as float
  float* outLogits; // [16,32,8193]
  float* src; float* tmpv; float* caC; float* x; float* q;
  float* aout; float* h1; float* kcache; float* vcache;
};

__device__ __forceinline__ float wred(float v) {
#pragma unroll
  for (int off = 32; off; off >>= 1) v += __shfl_down(v, off, 64);
  return v;
}

// dot over K=512: lane holds x[lane*4..+3] and x[256+lane*4..+3]
__device__ __forceinline__ float dot512(const float* __restrict__ wr,
                                        const float4& x0, const float4& x1, int lane) {
  float4 w0 = *(const float4*)(wr + lane * 4);
  float4 w1 = *(const float4*)(wr + 256 + lane * 4);
  float acc = w0.x * x0.x + w0.y * x0.y + w0.z * x0.z + w0.w * x0.w
            + w1.x * x1.x + w1.y * x1.y + w1.z * x1.z + w1.w * x1.w;
  return wred(acc);
}

__device__ __forceinline__ float pe_val(int t, int i) {
  int j2 = t & ~1;
  float div = expf((float)j2 * (-9.210340371976184f / 512.0f));
  float ang = (float)i * div;
  return (t & 1) ? cosf(ang) : sinf(ang);
}

__device__ void block_ln(float* s, const float* __restrict__ g,
                         const float* __restrict__ bb, int tid, float* red) {
  float ls = 0.f, lq = 0.f;
  for (int t = tid; t < Dm; t += NT) { float v = s[t]; ls += v; lq += v * v; }
  ls = wred(ls); lq = wred(lq);
  int wv = tid >> 6, lane = tid & 63;
  if (lane == 0) { red[wv] = ls; red[4 + wv] = lq; }
  __syncthreads();
  float sum = red[0] + red[1] + red[2] + red[3];
  float sq  = red[4] + red[5] + red[6] + red[7];
  float mean = sum * (1.f / Dm);
  float var  = sq * (1.f / Dm) - mean * mean;
  float inv  = 1.f / sqrtf(var + 1e-5f);
  __syncthreads();
  for (int t = tid; t < Dm; t += NT) s[t] = (s[t] - mean) * inv * g[t] + bb[t];
}

__global__ __launch_bounds__(NT, 2) void mega(Args a) {
  cg::grid_group grid = cg::this_grid();
  const int tid  = threadIdx.x;
  const int bid  = blockIdx.x;
  const int lane = tid & 63;
  const int wave = tid >> 6;
  const int gw   = bid * 4 + wave;   // global wave id
  const int ngw  = NB * 4;           // 1024 waves; multiple of 32 -> (gw&31) fixed per wave
  __shared__ float smem[544];

  // ---- setup: src (cross-attn memory) + step-0 embedding (start token) ----
  if (bid < Bn) {
    const int b = bid;
    for (int t = tid; t < Dm; t += NT) {
      float s = 0.f;
#pragma unroll
      for (int ty = 0; ty < 8; ++ty) {
        int idx = a.meanings[b * 8 + ty] + ty * 32;
        s += a.emb_table[(size_t)idx * Dm + t];
      }
      a.src[b * Dm + t] = s;
      a.x[b * Dm + t] = a.v2e_w[(size_t)(V1 - 1) * Dm + t] + pe_val(t, 0);
    }
  }
  grid.sync();

  // ---- setup: catmp = Wv*src + bv (both layers), scratch in h1 ----
  {
    float* catmp = a.h1;
    const int total = NL * Dm * Bn;
    for (int d = gw; d < total; d += ngw) {
      int b = d & 31, r = d >> 5, n = r & 511, l = r >> 9;
      const float* xr = a.src + b * Dm;
      float4 x0 = *(const float4*)(xr + lane * 4);
      float4 x1 = *(const float4*)(xr + 256 + lane * 4);
      const float* wr = a.ca_qkv_w + ((size_t)l * 3 * Dm + 2 * Dm + n) * Dm;
      float acc = dot512(wr, x0, x1, lane);
      if (lane == 0) catmp[(l * Bn + b) * Dm + n] = acc + a.ca_qkv_b[l * 3 * Dm + 2 * Dm + n];
    }
  }
  grid.sync();

  // ---- setup: caC = Wout*catmp + bout (cross-attn constant; softmax over 1 key == 1) ----
  {
    const float* catmp = a.h1;
    const int total = NL * Dm * Bn;
    for (int d = gw; d < total; d += ngw) {
      int b = d & 31, r = d >> 5, n = r & 511, l = r >> 9;
      const float* xr = catmp + (l * Bn + b) * Dm;
      float4 x0 = *(const float4*)(xr + lane * 4);
      float4 x1 = *(const float4*)(xr + 256 + lane * 4);
      const float* wr = a.ca_out_w + ((size_t)l * Dm + n) * Dm;
      float acc = dot512(wr, x0, x1, lane);
      if (lane == 0) a.caC[(l * Bn + b) * Dm + n] = acc + a.ca_out_b[l * Dm + n];
    }
  }
  grid.sync();

  for (int i = 0; i < Lq; ++i) {
    for (int l = 0; l < NL; ++l) {
      float* kc = a.kcache + (size_t)l * Lq * Bn * Dm;
      float* vc = a.vcache + (size_t)l * Lq * Bn * Dm;

      // --- QKV (wide): 1536*32 dots, route q / k-slot / v-slot ---
      {
        const float* W = a.sa_qkv_w + (size_t)l * 3 * Dm * Dm;
        const float* bias = a.sa_qkv_b + l * 3 * Dm;
        const int b = gw & 31;
        const float* xr = a.x + b * Dm;
        float4 x0 = *(const float4*)(xr + lane * 4);
        float4 x1 = *(const float4*)(xr + 256 + lane * 4);
        float* kslot = kc + (size_t)i * Bn * Dm;
        float* vslot = vc + (size_t)i * Bn * Dm;
        const int total = 3 * Dm * Bn;
        for (int d = gw; d < total; d += ngw) {
          int n = d >> 5;
          float acc = dot512(W + (size_t)n * Dm, x0, x1, lane);
          if (lane == 0) {
            float rr = acc + bias[n];
            if (n < Dm)           a.q[b * Dm + n] = rr;
            else if (n < 2 * Dm)  kslot[b * Dm + (n - Dm)] = rr;
            else                  vslot[b * Dm + (n - 2 * Dm)] = rr;
          }
        }
      }
      grid.sync();

      // --- self-attn core (per-b block): scores + softmax + weighted V ---
      if (bid < Bn) {
        const int b = bid;
        float* sQ = smem; float* sS = smem + Dm;
        for (int t = tid; t < Dm; t += NT) sQ[t] = a.q[b * Dm + t];
        __syncthreads();
        float4 q0 = *(const float4*)(sQ + lane * 4);
        float4 q1 = *(const float4*)(sQ + 256 + lane * 4);
        for (int j = wave; j <= i; j += 4) {
          float acc = dot512(kc + ((size_t)j * Bn + b) * Dm, q0, q1, lane);
          if (lane == 0) sS[j] = acc * 0.04419417382415922f;  // 1/sqrt(512)
        }
        __syncthreads();
        if (tid == 0) {
          float m = -1e30f;
          for (int j = 0; j <= i; ++j) m = fmaxf(m, sS[j]);
          float s = 0.f;
          for (int j = 0; j <= i; ++j) { float e = expf(sS[j] - m); sS[j] = e; s += e; }
          float inv = 1.f / s;
          for (int j = 0; j <= i; ++j) sS[j] *= inv;
        }
        __syncthreads();
        for (int t = tid; t < Dm; t += NT) {
          float acc = 0.f;
          for (int j = 0; j <= i; ++j) acc += sS[j] * vc[((size_t)j * Bn + b) * Dm + t];
          a.aout[b * Dm + t] = acc;
        }
      }
      grid.sync();

      // --- out-projection (wide) -> tmpv ---
      {
        const int b = gw & 31;
        const float* xr = a.aout + b * Dm;
        float4 x0 = *(const float4*)(xr + lane * 4);
        float4 x1 = *(const float4*)(xr + 256 + lane * 4);
        const float* W = a.sa_out_w + (size_t)l * Dm * Dm;
        const int total = Dm * Bn;
        for (int d = gw; d < total; d += ngw) {
          int n = d >> 5;
          float acc = dot512(W + (size_t)n * Dm, x0, x1, lane);
          if (lane == 0) a.tmpv[b * Dm + n] = acc + a.sa_out_b[l * Dm + n];
        }
      }
      grid.sync();

      // --- residual + LN1 + add-caC + LN2 (per-b block) ---
      if (bid < Bn) {
        const int b = bid;
        float* sR = smem; float* red = smem + 512;
        for (int t = tid; t < Dm; t += NT) sR[t] = a.x[b * Dm + t] + a.tmpv[b * Dm + t];
        __syncthreads();
        block_ln(sR, a.ln1_g + l * Dm, a.ln1_b + l * Dm, tid, red);
        __syncthreads();
        for (int t = tid; t < Dm; t += NT) sR[t] += a.caC[(l * Bn + b) * Dm + t];
        __syncthreads();
        block_ln(sR, a.ln2_g + l * Dm, a.ln2_b + l * Dm, tid, red);
        __syncthreads();
        for (int t = tid; t < Dm; t += NT) a.x[b * Dm + t] = sR[t];
      }
      grid.sync();

      // --- FFN1 (wide, relu) -> h1 ---
      {
        const int b = gw & 31;
        const float* xr = a.x + b * Dm;
        float4 x0 = *(const float4*)(xr + lane * 4);
        float4 x1 = *(const float4*)(xr + 256 + lane * 4);
        const float* W = a.ffn_w1 + (size_t)l * DFF * Dm;
        const float* bias = a.ffn_b1 + l * DFF;
        const int total = DFF * Bn;
        for (int d = gw; d < total; d += ngw) {
          int n = d >> 5;
          float acc = dot512(W + (size_t)n * Dm, x0, x1, lane);
          if (lane == 0) a.h1[b * DFF + n] = fmaxf(acc + bias[n], 0.f);
        }
      }
      grid.sync();

      // --- FFN2 (wide, K=2048) -> tmpv ---
      {
        const int b = gw & 31;
        const float* hr = a.h1 + b * DFF;
        float4 xc[8];
#pragma unroll
        for (int jj = 0; jj < 8; ++jj) xc[jj] = *(const float4*)(hr + jj * 256 + lane * 4);
        const float* W = a.ffn_w2 + (size_t)l * Dm * DFF;
        const float* bias = a.ffn_b2 + l * Dm;
        const int total = Dm * Bn;
        for (int d = gw; d < total; d += ngw) {
          int n = d >> 5;
          const float* wr = W + (size_t)n * DFF;
          float acc = 0.f;
#pragma unroll
          for (int jj = 0; jj < 8; ++jj) {
            float4 w4 = *(const float4*)(wr + jj * 256 + lane * 4);
            acc += w4.x * xc[jj].x + w4.y * xc[jj].y + w4.z * xc[jj].z + w4.w * xc[jj].w;
          }
          acc = wred(acc);
          if (lane == 0) a.tmpv[b * Dm + n] = acc + bias[n];
        }
      }
      grid.sync();

      // --- residual + LN3 (per-b block) ---
      if (bid < Bn) {
        const int b = bid;
        float* sR = smem; float* red = smem + 512;
        for (int t = tid; t < Dm; t += NT) sR[t] = a.x[b * Dm + t] + a.tmpv[b * Dm + t];
        __syncthreads();
        block_ln(sR, a.ln3_g + l * Dm, a.ln3_b + l * Dm, tid, red);
        __syncthreads();
        for (int t = tid; t < Dm; t += NT) a.x[b * Dm + t] = sR[t];
      }
      grid.sync();
    }

    // --- logits (wide): 8193*32 dots -> d_out ---
    {
      const int b = gw & 31;
      const float* xr = a.x + b * Dm;
      float4 x0 = *(const float4*)(xr + lane * 4);
      float4 x1 = *(const float4*)(xr + 256 + lane * 4);
      float* lg = a.outLogits + (size_t)i * Bn * V1;
      const int total = V1 * Bn;
      for (int d = gw; d < total; d += ngw) {
        int n = d >> 5;
        float acc = dot512(a.e2v_w + (size_t)n * Dm, x0, x1, lane);
        if (lane == 0) lg[(size_t)b * V1 + n] = acc + a.e2v_b[n];
      }
    }
    grid.sync();

    // --- argmax (per-b block) + fused next-step embedding ---
    if (bid < Bn) {
      const int b = bid;
      const float* row = a.outLogits + (size_t)(i * Bn + b) * V1;
      float best = -1e30f; int bi = V1;
      for (int v = tid; v < V1; v += NT) {
        float val = row[v];
        if (val > best) { best = val; bi = v; }  // ascending stride: first-max kept
      }
      float* sv = smem; int* si = (int*)(smem + 256);
      sv[tid] = best; si[tid] = bi;
      __syncthreads();
      for (int off = 128; off > 0; off >>= 1) {
        if (tid < off) {
          float v2 = sv[tid + off]; int i2 = si[tid + off];
          if (v2 > sv[tid] || (v2 == sv[tid] && i2 < si[tid])) { sv[tid] = v2; si[tid] = i2; }
        }
        __syncthreads();
      }
      int tok = si[0];
      if (tid == 0) a.outToks[i * Bn + b] = (float)tok;
      if (i + 1 < Lq) {
        for (int t = tid; t < Dm; t += NT)
          a.x[b * Dm + t] = a.v2e_w[(size_t)tok * Dm + t] + pe_val(t, i + 1);
      }
    }
    grid.sync();
  }
}

}  // namespace

extern "C" void kernel_launch(void* const* d_in, const int* in_sizes, int n_in,
                              void* d_out, int out_size, void* d_ws, size_t ws_size,
                              hipStream_t stream) {
  (void)in_sizes; (void)n_in; (void)out_size; (void)ws_size;

  float* out = (float*)d_out;

  float* ws = (float*)d_ws;
  Args a;
  a.meanings  = (const int*)d_in[0];
  a.emb_table = (const float*)d_in[1];
  a.v2e_w     = (const float*)d_in[2];
  a.e2v_w     = (const float*)d_in[3];
  a.e2v_b     = (const float*)d_in[4];
  a.sa_qkv_w  = (const float*)d_in[5];
  a.sa_qkv_b  = (const float*)d_in[6];
  a.sa_out_w  = (const float*)d_in[7];
  a.sa_out_b  = (const float*)d_in[8];
  a.ca_qkv_w  = (const float*)d_in[9];
  a.ca_qkv_b  = (const float*)d_in[10];
  a.ca_out_w  = (const float*)d_in[11];
  a.ca_out_b  = (const float*)d_in[12];
  a.ffn_w1    = (const float*)d_in[13];
  a.ffn_b1    = (const float*)d_in[14];
  a.ffn_w2    = (const float*)d_in[15];
  a.ffn_b2    = (const float*)d_in[16];
  a.ln1_g     = (const float*)d_in[17];
  a.ln1_b     = (const float*)d_in[18];
  a.ln2_g     = (const float*)d_in[19];
  a.ln2_b     = (const float*)d_in[20];
  a.ln3_g     = (const float*)d_in[21];
  a.ln3_b     = (const float*)d_in[22];
  a.outToks   = out;
  a.outLogits = out + Lq * Bn;

  a.src    = ws;                       // 16384
  a.tmpv   = a.src    + Bn * Dm;       // 16384
  a.caC    = a.tmpv   + Bn * Dm;       // 32768
  a.x      = a.caC    + NL * Bn * Dm;  // 16384
  a.q      = a.x      + Bn * Dm;       // 16384
  a.aout   = a.q      + Bn * Dm;       // 16384
  a.h1     = a.aout   + Bn * Dm;       // 65536 (doubles as ca scratch in setup)
  a.kcache = a.h1     + Bn * DFF;      // 262144
  a.vcache = a.kcache + (size_t)NL * Lq * Bn * Dm;  // 262144

  void* kp[] = { (void*)&a };
  hipLaunchCooperativeKernel((const void*)mega, dim3(NB), dim3(NT), kp, 0, stream);
}

// Round 4
// 9445.824 us; speedup vs baseline: 1.4725x; 1.4725x over previous
//
#include <hip/hip_runtime.h>
#include <hip/hip_cooperative_groups.h>
#include <cmath>

namespace cg = cooperative_groups;

namespace {

constexpr int Dm  = 512;
constexpr int Bn  = 32;
constexpr int Lq  = 16;
constexpr int V1  = 8193;
constexpr int DFF = 2048;
constexpr int NL  = 2;
constexpr int NB  = 256;    // blocks = CUs (1 block/CU)
constexpr int NT  = 1024;   // threads/block (16 waves) -> 16 waves/CU
constexpr int NGW = NB * (NT / 64);  // 4096 global waves

struct Args {
  const int*   meanings;
  const float* emb_table;
  const float* v2e_w;
  const float* e2v_w;  const float* e2v_b;
  const float* sa_qkv_w; const float* sa_qkv_b;
  const float* sa_out_w; const float* sa_out_b;
  const float* ca_qkv_w; const float* ca_qkv_b;
  const float* ca_out_w; const float* ca_out_b;
  const float* ffn_w1; const float* ffn_b1;
  const float* ffn_w2; const float* ffn_b2;
  const float* ln1_g; const float* ln1_b;
  const float* ln2_g; const float* ln2_b;
  const float* ln3_g; const float* ln3_b;
  float* outToks;   // [16,32] as float
  float* outLogits; // [16,32,8193]
  float* src; float* tmpv; float* caC; float* x; float* q;
  float* aout; float* h1; float* kcache; float* vcache;
};

__device__ __forceinline__ float wred(float v) {
#pragma unroll
  for (int off = 32; off; off >>= 1) v += __shfl_down(v, off, 64);
  return v;
}

__device__ __forceinline__ float pe_val(int t, int i) {
  int j2 = t & ~1;
  float div = expf((float)j2 * (-9.210340371976184f / 512.0f));
  float ang = (float)i * div;
  return (t & 1) ? cosf(ang) : sinf(ang);
}

// load x-fragments for 8 consecutive batch rows starting at b0 (stride Dm)
__device__ __forceinline__ void load_frag8(const float* __restrict__ base, int b0,
                                           int lane, float4* x0, float4* x1) {
#pragma unroll
  for (int j = 0; j < 8; ++j) {
    const float* xr = base + (size_t)(b0 + j) * Dm;
    x0[j] = *(const float4*)(xr + lane * 4);
    x1[j] = *(const float4*)(xr + 256 + lane * 4);
  }
}

// one weight row (K=512) dotted against 8 x-fragments; acc valid on lane 0
__device__ __forceinline__ void row_dot8(const float* __restrict__ wr,
                                         const float4* x0, const float4* x1,
                                         int lane, float* acc) {
  float4 w0 = *(const float4*)(wr + lane * 4);
  float4 w1 = *(const float4*)(wr + 256 + lane * 4);
#pragma unroll
  for (int j = 0; j < 8; ++j) {
    float a = w0.x * x0[j].x + w0.y * x0[j].y + w0.z * x0[j].z + w0.w * x0[j].w
            + w1.x * x1[j].x + w1.y * x1[j].y + w1.z * x1[j].z + w1.w * x1[j].w;
    acc[j] = wred(a);
  }
}

__device__ void block_ln(float* s, const float* __restrict__ g,
                         const float* __restrict__ bb, int tid, float* red) {
  float ls = 0.f, lq = 0.f;
  for (int t = tid; t < Dm; t += NT) { float v = s[t]; ls += v; lq += v * v; }
  ls = wred(ls); lq = wred(lq);
  int wv = tid >> 6, lane = tid & 63;
  if (lane == 0) { red[wv] = ls; red[16 + wv] = lq; }
  __syncthreads();
  float sum = 0.f, sq = 0.f;
#pragma unroll
  for (int k = 0; k < 16; ++k) { sum += red[k]; sq += red[16 + k]; }
  float mean = sum * (1.f / Dm);
  float var  = sq * (1.f / Dm) - mean * mean;
  float inv  = 1.f / sqrtf(var + 1e-5f);
  __syncthreads();
  for (int t = tid; t < Dm; t += NT) s[t] = (s[t] - mean) * inv * g[t] + bb[t];
}

__global__ __launch_bounds__(NT, 4) void mega(Args a) {
  cg::grid_group grid = cg::this_grid();
  const int tid  = threadIdx.x;
  const int bid  = blockIdx.x;
  const int lane = tid & 63;
  const int wave = tid >> 6;             // 0..15
  const int gw   = bid * 16 + wave;      // 0..4095
  const int g4   = gw & 3;               // b-group for 8-b stages (fixed per wave)
  __shared__ float smem[2080];

  // ---- setup: src (cross-attn memory) + step-0 embedding (start token) ----
  if (bid < Bn) {
    const int b = bid;
    for (int t = tid; t < Dm; t += NT) {
      float s = 0.f;
#pragma unroll
      for (int ty = 0; ty < 8; ++ty) {
        int idx = a.meanings[b * 8 + ty] + ty * 32;
        s += a.emb_table[(size_t)idx * Dm + t];
      }
      a.src[b * Dm + t] = s;
      a.x[b * Dm + t] = a.v2e_w[(size_t)(V1 - 1) * Dm + t] + pe_val(t, 0);
    }
  }
  grid.sync();

  // ---- setup: catmp = Wv*src + bv (both layers) -> scratch in h1 ----
  {
    float* catmp = a.h1;
    float4 x0[8], x1[8];
    load_frag8(a.src, g4 * 8, lane, x0, x1);
    int u = gw;                            // NL*Dm*4 == 4096: exactly one unit/wave
    int r = u >> 2, n = r & 511, l = r >> 9;
    const float* wr = a.ca_qkv_w + ((size_t)l * 3 * Dm + 2 * Dm + n) * Dm;
    float acc[8];
    row_dot8(wr, x0, x1, lane, acc);
    if (lane == 0) {
      float bn = a.ca_qkv_b[l * 3 * Dm + 2 * Dm + n];
#pragma unroll
      for (int j = 0; j < 8; ++j) catmp[(l * Bn + g4 * 8 + j) * Dm + n] = acc[j] + bn;
    }
  }
  grid.sync();

  // ---- setup: caC = Wout*catmp + bout (softmax over 1 key == 1) ----
  {
    const float* catmp = a.h1;
    int u = gw;
    int r = u >> 2, n = r & 511, l = r >> 9;
    float4 x0[8], x1[8];
    load_frag8(catmp + (size_t)l * Bn * Dm, g4 * 8, lane, x0, x1);
    const float* wr = a.ca_out_w + ((size_t)l * Dm + n) * Dm;
    float acc[8];
    row_dot8(wr, x0, x1, lane, acc);
    if (lane == 0) {
      float bn = a.ca_out_b[l * Dm + n];
#pragma unroll
      for (int j = 0; j < 8; ++j) a.caC[(l * Bn + g4 * 8 + j) * Dm + n] = acc[j] + bn;
    }
  }
  grid.sync();

  for (int i = 0; i < Lq; ++i) {
    for (int l = 0; l < NL; ++l) {
      float* kc = a.kcache + (size_t)l * Lq * Bn * Dm;
      float* vc = a.vcache + (size_t)l * Lq * Bn * Dm;

      // --- QKV: 1536 rows x 8 b per wave; each row read by exactly one block ---
      {
        const float* W = a.sa_qkv_w + (size_t)l * 3 * Dm * Dm;
        const float* bias = a.sa_qkv_b + l * 3 * Dm;
        float* kslot = kc + (size_t)i * Bn * Dm;
        float* vslot = vc + (size_t)i * Bn * Dm;
        float4 x0[8], x1[8];
        load_frag8(a.x, g4 * 8, lane, x0, x1);
        for (int u = gw; u < 3 * Dm * 4; u += NGW) {
          int n = u >> 2;
          float acc[8];
          row_dot8(W + (size_t)n * Dm, x0, x1, lane, acc);
          if (lane == 0) {
            float bn = bias[n];
#pragma unroll
            for (int j = 0; j < 8; ++j) {
              int b = g4 * 8 + j;
              float rr = acc[j] + bn;
              if (n < Dm)           a.q[b * Dm + n] = rr;
              else if (n < 2 * Dm)  kslot[b * Dm + (n - Dm)] = rr;
              else                  vslot[b * Dm + (n - 2 * Dm)] = rr;
            }
          }
        }
      }
      grid.sync();

      // --- self-attn core (per-b block) ---
      if (bid < Bn) {
        const int b = bid;
        float* sQ = smem; float* sS = smem + Dm;
        for (int t = tid; t < Dm; t += NT) sQ[t] = a.q[b * Dm + t];
        __syncthreads();
        float4 q0 = *(const float4*)(sQ + lane * 4);
        float4 q1 = *(const float4*)(sQ + 256 + lane * 4);
        for (int j = wave; j <= i; j += 16) {
          const float* kr = kc + ((size_t)j * Bn + b) * Dm;
          float4 k0 = *(const float4*)(kr + lane * 4);
          float4 k1 = *(const float4*)(kr + 256 + lane * 4);
          float acc = k0.x * q0.x + k0.y * q0.y + k0.z * q0.z + k0.w * q0.w
                    + k1.x * q1.x + k1.y * q1.y + k1.z * q1.z + k1.w * q1.w;
          acc = wred(acc);
          if (lane == 0) sS[j] = acc * 0.04419417382415922f;  // 1/sqrt(512)
        }
        __syncthreads();
        if (tid == 0) {
          float m = -1e30f;
          for (int j = 0; j <= i; ++j) m = fmaxf(m, sS[j]);
          float s = 0.f;
          for (int j = 0; j <= i; ++j) { float e = expf(sS[j] - m); sS[j] = e; s += e; }
          float inv = 1.f / s;
          for (int j = 0; j <= i; ++j) sS[j] *= inv;
        }
        __syncthreads();
        for (int t = tid; t < Dm; t += NT) {
          float acc = 0.f;
          for (int j = 0; j <= i; ++j) acc += sS[j] * vc[((size_t)j * Bn + b) * Dm + t];
          a.aout[b * Dm + t] = acc;
        }
      }
      grid.sync();

      // --- out-projection: 512 rows (waves 0..2047) ---
      if (gw < Dm * 4) {
        float4 x0[8], x1[8];
        load_frag8(a.aout, g4 * 8, lane, x0, x1);
        int n = gw >> 2;
        const float* wr = a.sa_out_w + (size_t)l * Dm * Dm + (size_t)n * Dm;
        float acc[8];
        row_dot8(wr, x0, x1, lane, acc);
        if (lane == 0) {
          float bn = a.sa_out_b[l * Dm + n];
#pragma unroll
          for (int j = 0; j < 8; ++j) a.tmpv[(g4 * 8 + j) * Dm + n] = acc[j] + bn;
        }
      }
      grid.sync();

      // --- residual + LN1 + add-caC + LN2 (per-b block) ---
      if (bid < Bn) {
        const int b = bid;
        float* sR = smem; float* red = smem + 512;
        for (int t = tid; t < Dm; t += NT) sR[t] = a.x[b * Dm + t] + a.tmpv[b * Dm + t];
        __syncthreads();
        block_ln(sR, a.ln1_g + l * Dm, a.ln1_b + l * Dm, tid, red);
        __syncthreads();
        for (int t = tid; t < Dm; t += NT) sR[t] += a.caC[(l * Bn + b) * Dm + t];
        __syncthreads();
        block_ln(sR, a.ln2_g + l * Dm, a.ln2_b + l * Dm, tid, red);
        __syncthreads();
        for (int t = tid; t < Dm; t += NT) a.x[b * Dm + t] = sR[t];
      }
      grid.sync();

      // --- FFN1 (relu): 2048 rows, 2 rows/wave ---
      {
        const float* W = a.ffn_w1 + (size_t)l * DFF * Dm;
        const float* bias = a.ffn_b1 + l * DFF;
        float4 x0[8], x1[8];
        load_frag8(a.x, g4 * 8, lane, x0, x1);
        for (int u = gw; u < DFF * 4; u += NGW) {
          int n = u >> 2;
          float acc[8];
          row_dot8(W + (size_t)n * Dm, x0, x1, lane, acc);
          if (lane == 0) {
            float bn = bias[n];
#pragma unroll
            for (int j = 0; j < 8; ++j)
              a.h1[(g4 * 8 + j) * DFF + n] = fmaxf(acc[j] + bn, 0.f);
          }
        }
      }
      grid.sync();

      // --- FFN2 (K=2048): 512 rows x 2 b per wave (16 groups/row, same block) ---
      {
        const float* W = a.ffn_w2 + (size_t)l * Dm * DFF;
        const float* bias = a.ffn_b2 + l * Dm;
        const int g16 = gw & 15;           // fixed per wave
        const int b0 = g16 * 2;
        float4 xa[8], xb[8];
        const float* ha = a.h1 + (size_t)b0 * DFF;
        const float* hb = a.h1 + (size_t)(b0 + 1) * DFF;
#pragma unroll
        for (int jj = 0; jj < 8; ++jj) {
          xa[jj] = *(const float4*)(ha + jj * 256 + lane * 4);
          xb[jj] = *(const float4*)(hb + jj * 256 + lane * 4);
        }
        for (int u = gw; u < Dm * 16; u += NGW) {
          int n = u >> 4;
          const float* wr = W + (size_t)n * DFF;
          float pa = 0.f, pb = 0.f;
#pragma unroll
          for (int jj = 0; jj < 8; ++jj) {
            float4 w4 = *(const float4*)(wr + jj * 256 + lane * 4);
            pa += w4.x * xa[jj].x + w4.y * xa[jj].y + w4.z * xa[jj].z + w4.w * xa[jj].w;
            pb += w4.x * xb[jj].x + w4.y * xb[jj].y + w4.z * xb[jj].z + w4.w * xb[jj].w;
          }
          pa = wred(pa); pb = wred(pb);
          if (lane == 0) {
            float bn = bias[n];
            a.tmpv[b0 * Dm + n]       = pa + bn;
            a.tmpv[(b0 + 1) * Dm + n] = pb + bn;
          }
        }
      }
      grid.sync();

      // --- residual + LN3 (per-b block) ---
      if (bid < Bn) {
        const int b = bid;
        float* sR = smem; float* red = smem + 512;
        for (int t = tid; t < Dm; t += NT) sR[t] = a.x[b * Dm + t] + a.tmpv[b * Dm + t];
        __syncthreads();
        block_ln(sR, a.ln3_g + l * Dm, a.ln3_b + l * Dm, tid, red);
        __syncthreads();
        for (int t = tid; t < Dm; t += NT) a.x[b * Dm + t] = sR[t];
      }
      grid.sync();
    }

    // --- logits: 8193 rows x 8 b per wave -> d_out ---
    {
      float* lg = a.outLogits + (size_t)i * Bn * V1;
      float4 x0[8], x1[8];
      load_frag8(a.x, g4 * 8, lane, x0, x1);
      for (int u = gw; u < V1 * 4; u += NGW) {
        int n = u >> 2;
        float acc[8];
        row_dot8(a.e2v_w + (size_t)n * Dm, x0, x1, lane, acc);
        if (lane == 0) {
          float bn = a.e2v_b[n];
#pragma unroll
          for (int j = 0; j < 8; ++j) lg[(size_t)(g4 * 8 + j) * V1 + n] = acc[j] + bn;
        }
      }
    }
    grid.sync();

    // --- argmax (per-b block) + fused next-step embedding ---
    if (bid < Bn) {
      const int b = bid;
      const float* row = a.outLogits + (size_t)(i * Bn + b) * V1;
      float best = -1e30f; int bi = V1;
      for (int v = tid; v < V1; v += NT) {
        float val = row[v];
        if (val > best) { best = val; bi = v; }  // ascending stride: first-max kept
      }
      float* sv = smem; int* si = (int*)(smem + 1024);
      sv[tid] = best; si[tid] = bi;
      __syncthreads();
      for (int off = 512; off > 0; off >>= 1) {
        if (tid < off) {
          float v2 = sv[tid + off]; int i2 = si[tid + off];
          if (v2 > sv[tid] || (v2 == sv[tid] && i2 < si[tid])) { sv[tid] = v2; si[tid] = i2; }
        }
        __syncthreads();
      }
      int tok = si[0];
      if (tid == 0) a.outToks[i * Bn + b] = (float)tok;
      if (i + 1 < Lq) {
        for (int t = tid; t < Dm; t += NT)
          a.x[b * Dm + t] = a.v2e_w[(size_t)tok * Dm + t] + pe_val(t, i + 1);
      }
    }
    grid.sync();
  }
}

}  // namespace

extern "C" void kernel_launch(void* const* d_in, const int* in_sizes, int n_in,
                              void* d_out, int out_size, void* d_ws, size_t ws_size,
                              hipStream_t stream) {
  (void)in_sizes; (void)n_in; (void)out_size; (void)ws_size;

  float* out = (float*)d_out;
  float* ws = (float*)d_ws;

  Args a;
  a.meanings  = (const int*)d_in[0];
  a.emb_table = (const float*)d_in[1];
  a.v2e_w     = (const float*)d_in[2];
  a.e2v_w     = (const float*)d_in[3];
  a.e2v_b     = (const float*)d_in[4];
  a.sa_qkv_w  = (const float*)d_in[5];
  a.sa_qkv_b  = (const float*)d_in[6];
  a.sa_out_w  = (const float*)d_in[7];
  a.sa_out_b  = (const float*)d_in[8];
  a.ca_qkv_w  = (const float*)d_in[9];
  a.ca_qkv_b  = (const float*)d_in[10];
  a.ca_out_w  = (const float*)d_in[11];
  a.ca_out_b  = (const float*)d_in[12];
  a.ffn_w1    = (const float*)d_in[13];
  a.ffn_b1    = (const float*)d_in[14];
  a.ffn_w2    = (const float*)d_in[15];
  a.ffn_b2    = (const float*)d_in[16];
  a.ln1_g     = (const float*)d_in[17];
  a.ln1_b     = (const float*)d_in[18];
  a.ln2_g     = (const float*)d_in[19];
  a.ln2_b     = (const float*)d_in[20];
  a.ln3_g     = (const float*)d_in[21];
  a.ln3_b     = (const float*)d_in[22];
  a.outToks   = out;
  a.outLogits = out + Lq * Bn;

  a.src    = ws;
  a.tmpv   = a.src    + Bn * Dm;
  a.caC    = a.tmpv   + Bn * Dm;
  a.x      = a.caC    + NL * Bn * Dm;
  a.q      = a.x      + Bn * Dm;
  a.aout   = a.q      + Bn * Dm;
  a.h1     = a.aout   + Bn * Dm;       // doubles as ca scratch in setup
  a.kcache = a.h1     + Bn * DFF;
  a.vcache = a.kcache + (size_t)NL * Lq * Bn * Dm;

  void* kp[] = { (void*)&a };
  hipLaunchCooperativeKernel((const void*)mega, dim3(NB), dim3(NT), kp, 0, stream);
}

// Round 5
// 5111.132 us; speedup vs baseline: 2.7213x; 1.8481x over previous
//
#include <hip/hip_runtime.h>
#include <cmath>

namespace {

constexpr int Dm  = 512;
constexpr int Bn  = 32;
constexpr int Lq  = 16;
constexpr int V1  = 8193;
constexpr int DFF = 2048;
constexpr int NL  = 2;
constexpr int NB  = 256;    // blocks = CUs (1 block/CU)
constexpr int NT  = 1024;   // threads/block (16 waves) -> 16 waves/CU
constexpr int NGW = NB * (NT / 64);  // 4096 global waves

struct Args {
  const int*   meanings;
  const float* emb_table;
  const float* v2e_w;
  const float* e2v_w;  const float* e2v_b;
  const float* sa_qkv_w; const float* sa_qkv_b;
  const float* sa_out_w; const float* sa_out_b;
  const float* ca_qkv_w; const float* ca_qkv_b;
  const float* ca_out_w; const float* ca_out_b;
  const float* ffn_w1; const float* ffn_b1;
  const float* ffn_w2; const float* ffn_b2;
  const float* ln1_g; const float* ln1_b;
  const float* ln2_g; const float* ln2_b;
  const float* ln3_g; const float* ln3_b;
  float* outToks;   // [16,32] as float
  float* outLogits; // [16,32,8193]
  unsigned* barArrive; unsigned* barGen;
  float* src; float* tmpv; float* caC; float* x; float* q;
  float* aout; float* h1; float* kcache; float* vcache;
  float* partV; int* partI;
};

__device__ __forceinline__ float wred(float v) {
#pragma unroll
  for (int off = 32; off; off >>= 1) v += __shfl_down(v, off, 64);
  return v;
}

// --- hand-rolled grid barrier (replaces cg::grid_group::sync, ~30us -> ~3us)
// master-block pattern: blocks store epoch into their slot; block 0 detects
// all-arrived and releases `gen`; everyone polls gen. Fences give device-scope
// release/acquire (same semantics grid.sync provided).
__device__ __forceinline__ void gbar(unsigned* arrive, unsigned* gen,
                                     unsigned e, int bid, int tid) {
  __syncthreads();
  if (bid == 0) {
    if (tid > 0 && tid < NB) {
      while (__hip_atomic_load(&arrive[tid], __ATOMIC_RELAXED,
                               __HIP_MEMORY_SCOPE_AGENT) < e) {}
    }
    __syncthreads();
    if (tid == 0) {
      __threadfence();  // acquire arrivals' data + release own writes
      __hip_atomic_store(gen, e, __ATOMIC_RELAXED, __HIP_MEMORY_SCOPE_AGENT);
    }
    __syncthreads();
  } else {
    if (tid == 0) {
      __threadfence();  // release this block's writes
      __hip_atomic_store(&arrive[bid], e, __ATOMIC_RELAXED,
                         __HIP_MEMORY_SCOPE_AGENT);
      while (__hip_atomic_load(gen, __ATOMIC_RELAXED,
                               __HIP_MEMORY_SCOPE_AGENT) < e) {
        __builtin_amdgcn_s_sleep(1);
      }
      __threadfence();  // acquire other blocks' writes
    }
    __syncthreads();
  }
}

__device__ __forceinline__ float pe_val(int t, int i) {
  int j2 = t & ~1;
  float div = expf((float)j2 * (-9.210340371976184f / 512.0f));
  float ang = (float)i * div;
  return (t & 1) ? cosf(ang) : sinf(ang);
}

// load x-fragments for 8 consecutive batch rows starting at b0 (stride Dm)
__device__ __forceinline__ void load_frag8(const float* __restrict__ base, int b0,
                                           int lane, float4* x0, float4* x1) {
#pragma unroll
  for (int j = 0; j < 8; ++j) {
    const float* xr = base + (size_t)(b0 + j) * Dm;
    x0[j] = *(const float4*)(xr + lane * 4);
    x1[j] = *(const float4*)(xr + 256 + lane * 4);
  }
}

// one weight row (K=512) dotted against 8 x-fragments; acc valid on lane 0
__device__ __forceinline__ void row_dot8(const float* __restrict__ wr,
                                         const float4* x0, const float4* x1,
                                         int lane, float* acc) {
  float4 w0 = *(const float4*)(wr + lane * 4);
  float4 w1 = *(const float4*)(wr + 256 + lane * 4);
#pragma unroll
  for (int j = 0; j < 8; ++j) {
    float a = w0.x * x0[j].x + w0.y * x0[j].y + w0.z * x0[j].z + w0.w * x0[j].w
            + w1.x * x1[j].x + w1.y * x1[j].y + w1.z * x1[j].z + w1.w * x1[j].w;
    acc[j] = wred(a);
  }
}

__device__ void block_ln(float* s, const float* __restrict__ g,
                         const float* __restrict__ bb, int tid, float* red) {
  float ls = 0.f, lq = 0.f;
  for (int t = tid; t < Dm; t += NT) { float v = s[t]; ls += v; lq += v * v; }
  ls = wred(ls); lq = wred(lq);
  int wv = tid >> 6, lane = tid & 63;
  if (lane == 0) { red[wv] = ls; red[16 + wv] = lq; }
  __syncthreads();
  float sum = 0.f, sq = 0.f;
#pragma unroll
  for (int k = 0; k < 16; ++k) { sum += red[k]; sq += red[16 + k]; }
  float mean = sum * (1.f / Dm);
  float var  = sq * (1.f / Dm) - mean * mean;
  float inv  = 1.f / sqrtf(var + 1e-5f);
  __syncthreads();
  for (int t = tid; t < Dm; t += NT) s[t] = (s[t] - mean) * inv * g[t] + bb[t];
}

__global__ __launch_bounds__(NT, 4) void mega(Args a) {
  const int tid  = threadIdx.x;
  const int bid  = blockIdx.x;
  const int lane = tid & 63;
  const int wave = tid >> 6;             // 0..15
  const int gw   = bid * 16 + wave;      // 0..4095
  const int g4   = gw & 3;               // b-group for 8-b stages (fixed per wave)
  unsigned ep = 0;
  __shared__ float smem[2080];
  unsigned* bAr = a.barArrive;
  unsigned* bGe = a.barGen;

  // ---- setup: src (cross-attn memory) + step-0 embedding (start token) ----
  if (bid < Bn) {
    const int b = bid;
    for (int t = tid; t < Dm; t += NT) {
      float s = 0.f;
#pragma unroll
      for (int ty = 0; ty < 8; ++ty) {
        int idx = a.meanings[b * 8 + ty] + ty * 32;
        s += a.emb_table[(size_t)idx * Dm + t];
      }
      a.src[b * Dm + t] = s;
      a.x[b * Dm + t] = a.v2e_w[(size_t)(V1 - 1) * Dm + t] + pe_val(t, 0);
    }
  }
  gbar(bAr, bGe, ++ep, bid, tid);

  // ---- setup: catmp = Wv*src + bv (both layers) -> scratch in h1 ----
  {
    float* catmp = a.h1;
    float4 x0[8], x1[8];
    load_frag8(a.src, g4 * 8, lane, x0, x1);
    int u = gw;                            // NL*Dm*4 == 4096: exactly one unit/wave
    int r = u >> 2, n = r & 511, l = r >> 9;
    const float* wr = a.ca_qkv_w + ((size_t)l * 3 * Dm + 2 * Dm + n) * Dm;
    float acc[8];
    row_dot8(wr, x0, x1, lane, acc);
    if (lane == 0) {
      float bn = a.ca_qkv_b[l * 3 * Dm + 2 * Dm + n];
#pragma unroll
      for (int j = 0; j < 8; ++j) catmp[(l * Bn + g4 * 8 + j) * Dm + n] = acc[j] + bn;
    }
  }
  gbar(bAr, bGe, ++ep, bid, tid);

  // ---- setup: caC = Wout*catmp + bout (softmax over 1 key == 1) ----
  {
    const float* catmp = a.h1;
    int u = gw;
    int r = u >> 2, n = r & 511, l = r >> 9;
    float4 x0[8], x1[8];
    load_frag8(catmp + (size_t)l * Bn * Dm, g4 * 8, lane, x0, x1);
    const float* wr = a.ca_out_w + ((size_t)l * Dm + n) * Dm;
    float acc[8];
    row_dot8(wr, x0, x1, lane, acc);
    if (lane == 0) {
      float bn = a.ca_out_b[l * Dm + n];
#pragma unroll
      for (int j = 0; j < 8; ++j) a.caC[(l * Bn + g4 * 8 + j) * Dm + n] = acc[j] + bn;
    }
  }
  gbar(bAr, bGe, ++ep, bid, tid);

  for (int i = 0; i < Lq; ++i) {
    for (int l = 0; l < NL; ++l) {
      float* kc = a.kcache + (size_t)l * Lq * Bn * Dm;
      float* vc = a.vcache + (size_t)l * Lq * Bn * Dm;

      // --- QKV: 1536 rows x 8 b per wave; each row read by exactly one block ---
      {
        const float* W = a.sa_qkv_w + (size_t)l * 3 * Dm * Dm;
        const float* bias = a.sa_qkv_b + l * 3 * Dm;
        float* kslot = kc + (size_t)i * Bn * Dm;
        float* vslot = vc + (size_t)i * Bn * Dm;
        float4 x0[8], x1[8];
        load_frag8(a.x, g4 * 8, lane, x0, x1);
        for (int u = gw; u < 3 * Dm * 4; u += NGW) {
          int n = u >> 2;
          float acc[8];
          row_dot8(W + (size_t)n * Dm, x0, x1, lane, acc);
          if (lane == 0) {
            float bn = bias[n];
#pragma unroll
            for (int j = 0; j < 8; ++j) {
              int b = g4 * 8 + j;
              float rr = acc[j] + bn;
              if (n < Dm)           a.q[b * Dm + n] = rr;
              else if (n < 2 * Dm)  kslot[b * Dm + (n - Dm)] = rr;
              else                  vslot[b * Dm + (n - 2 * Dm)] = rr;
            }
          }
        }
      }
      gbar(bAr, bGe, ++ep, bid, tid);

      // --- self-attn core (per-b block) ---
      if (bid < Bn) {
        const int b = bid;
        float* sQ = smem; float* sS = smem + Dm;
        for (int t = tid; t < Dm; t += NT) sQ[t] = a.q[b * Dm + t];
        __syncthreads();
        float4 q0 = *(const float4*)(sQ + lane * 4);
        float4 q1 = *(const float4*)(sQ + 256 + lane * 4);
        for (int j = wave; j <= i; j += 16) {
          const float* kr = kc + ((size_t)j * Bn + b) * Dm;
          float4 k0 = *(const float4*)(kr + lane * 4);
          float4 k1 = *(const float4*)(kr + 256 + lane * 4);
          float acc = k0.x * q0.x + k0.y * q0.y + k0.z * q0.z + k0.w * q0.w
                    + k1.x * q1.x + k1.y * q1.y + k1.z * q1.z + k1.w * q1.w;
          acc = wred(acc);
          if (lane == 0) sS[j] = acc * 0.04419417382415922f;  // 1/sqrt(512)
        }
        __syncthreads();
        if (tid == 0) {
          float m = -1e30f;
          for (int j = 0; j <= i; ++j) m = fmaxf(m, sS[j]);
          float s = 0.f;
          for (int j = 0; j <= i; ++j) { float e = expf(sS[j] - m); sS[j] = e; s += e; }
          float inv = 1.f / s;
          for (int j = 0; j <= i; ++j) sS[j] *= inv;
        }
        __syncthreads();
        for (int t = tid; t < Dm; t += NT) {
          float acc = 0.f;
          for (int j = 0; j <= i; ++j) acc += sS[j] * vc[((size_t)j * Bn + b) * Dm + t];
          a.aout[b * Dm + t] = acc;
        }
      }
      gbar(bAr, bGe, ++ep, bid, tid);

      // --- out-projection: 512 rows (waves 0..2047) ---
      if (gw < Dm * 4) {
        float4 x0[8], x1[8];
        load_frag8(a.aout, g4 * 8, lane, x0, x1);
        int n = gw >> 2;
        const float* wr = a.sa_out_w + (size_t)l * Dm * Dm + (size_t)n * Dm;
        float acc[8];
        row_dot8(wr, x0, x1, lane, acc);
        if (lane == 0) {
          float bn = a.sa_out_b[l * Dm + n];
#pragma unroll
          for (int j = 0; j < 8; ++j) a.tmpv[(g4 * 8 + j) * Dm + n] = acc[j] + bn;
        }
      }
      gbar(bAr, bGe, ++ep, bid, tid);

      // --- residual + LN1 + add-caC + LN2 (per-b block) ---
      if (bid < Bn) {
        const int b = bid;
        float* sR = smem; float* red = smem + 512;
        for (int t = tid; t < Dm; t += NT) sR[t] = a.x[b * Dm + t] + a.tmpv[b * Dm + t];
        __syncthreads();
        block_ln(sR, a.ln1_g + l * Dm, a.ln1_b + l * Dm, tid, red);
        __syncthreads();
        for (int t = tid; t < Dm; t += NT) sR[t] += a.caC[(l * Bn + b) * Dm + t];
        __syncthreads();
        block_ln(sR, a.ln2_g + l * Dm, a.ln2_b + l * Dm, tid, red);
        __syncthreads();
        for (int t = tid; t < Dm; t += NT) a.x[b * Dm + t] = sR[t];
      }
      gbar(bAr, bGe, ++ep, bid, tid);

      // --- FFN1 (relu): 2048 rows, 2 rows/wave ---
      {
        const float* W = a.ffn_w1 + (size_t)l * DFF * Dm;
        const float* bias = a.ffn_b1 + l * DFF;
        float4 x0[8], x1[8];
        load_frag8(a.x, g4 * 8, lane, x0, x1);
        for (int u = gw; u < DFF * 4; u += NGW) {
          int n = u >> 2;
          float acc[8];
          row_dot8(W + (size_t)n * Dm, x0, x1, lane, acc);
          if (lane == 0) {
            float bn = bias[n];
#pragma unroll
            for (int j = 0; j < 8; ++j)
              a.h1[(g4 * 8 + j) * DFF + n] = fmaxf(acc[j] + bn, 0.f);
          }
        }
      }
      gbar(bAr, bGe, ++ep, bid, tid);

      // --- FFN2 (K=2048): 512 rows x 2 b per wave (16 groups/row, same block) ---
      {
        const float* W = a.ffn_w2 + (size_t)l * Dm * DFF;
        const float* bias = a.ffn_b2 + l * Dm;
        const int g16 = gw & 15;           // fixed per wave
        const int b0 = g16 * 2;
        float4 xa[8], xb[8];
        const float* ha = a.h1 + (size_t)b0 * DFF;
        const float* hb = a.h1 + (size_t)(b0 + 1) * DFF;
#pragma unroll
        for (int jj = 0; jj < 8; ++jj) {
          xa[jj] = *(const float4*)(ha + jj * 256 + lane * 4);
          xb[jj] = *(const float4*)(hb + jj * 256 + lane * 4);
        }
        for (int u = gw; u < Dm * 16; u += NGW) {
          int n = u >> 4;
          const float* wr = W + (size_t)n * DFF;
          float pa = 0.f, pb = 0.f;
#pragma unroll
          for (int jj = 0; jj < 8; ++jj) {
            float4 w4 = *(const float4*)(wr + jj * 256 + lane * 4);
            pa += w4.x * xa[jj].x + w4.y * xa[jj].y + w4.z * xa[jj].z + w4.w * xa[jj].w;
            pb += w4.x * xb[jj].x + w4.y * xb[jj].y + w4.z * xb[jj].z + w4.w * xb[jj].w;
          }
          pa = wred(pa); pb = wred(pb);
          if (lane == 0) {
            float bn = bias[n];
            a.tmpv[b0 * Dm + n]       = pa + bn;
            a.tmpv[(b0 + 1) * Dm + n] = pb + bn;
          }
        }
      }
      gbar(bAr, bGe, ++ep, bid, tid);

      // --- residual + LN3 (per-b block) ---
      if (bid < Bn) {
        const int b = bid;
        float* sR = smem; float* red = smem + 512;
        for (int t = tid; t < Dm; t += NT) sR[t] = a.x[b * Dm + t] + a.tmpv[b * Dm + t];
        __syncthreads();
        block_ln(sR, a.ln3_g + l * Dm, a.ln3_b + l * Dm, tid, red);
        __syncthreads();
        for (int t = tid; t < Dm; t += NT) a.x[b * Dm + t] = sR[t];
      }
      gbar(bAr, bGe, ++ep, bid, tid);
    }

    // --- logits: 8193 rows x 8 b per wave -> d_out, with running argmax ---
    {
      float* lg = a.outLogits + (size_t)i * Bn * V1;
      float4 x0[8], x1[8];
      load_frag8(a.x, g4 * 8, lane, x0, x1);
      float pm[8]; int pidx[8];
#pragma unroll
      for (int j = 0; j < 8; ++j) { pm[j] = -1e30f; pidx[j] = 0; }
      for (int u = gw; u < V1 * 4; u += NGW) {
        int n = u >> 2;
        float acc[8];
        row_dot8(a.e2v_w + (size_t)n * Dm, x0, x1, lane, acc);
        if (lane == 0) {
          float bn = a.e2v_b[n];
#pragma unroll
          for (int j = 0; j < 8; ++j) {
            float val = acc[j] + bn;
            lg[(size_t)(g4 * 8 + j) * V1 + n] = val;
            if (val > pm[j]) { pm[j] = val; pidx[j] = n; }  // n ascending: first-max
          }
        }
      }
      if (lane == 0) {
#pragma unroll
        for (int j = 0; j < 8; ++j) {
          a.partV[gw * 8 + j] = pm[j];
          a.partI[gw * 8 + j] = pidx[j];
        }
      }
    }
    gbar(bAr, bGe, ++ep, bid, tid);

    // --- argmax combine over 1024 wave-partials (per-b block) + next embed ---
    if (bid < Bn) {
      const int b = bid;
      const int g4b = b >> 3, jb = b & 7;
      float* sv = smem; int* si = (int*)(smem + 1024);
      int w = g4b + tid * 4;               // the 1024 waves whose g4 == b>>3
      sv[tid] = a.partV[w * 8 + jb];
      si[tid] = a.partI[w * 8 + jb];
      __syncthreads();
      for (int off = 512; off > 0; off >>= 1) {
        if (tid < off) {
          float v2 = sv[tid + off]; int i2 = si[tid + off];
          if (v2 > sv[tid] || (v2 == sv[tid] && i2 < si[tid])) { sv[tid] = v2; si[tid] = i2; }
        }
        __syncthreads();
      }
      int tok = si[0];
      if (tid == 0) a.outToks[i * Bn + b] = (float)tok;
      if (i + 1 < Lq) {
        for (int t = tid; t < Dm; t += NT)
          a.x[b * Dm + t] = a.v2e_w[(size_t)tok * Dm + t] + pe_val(t, i + 1);
      }
    }
    gbar(bAr, bGe, ++ep, bid, tid);
  }
}

}  // namespace

extern "C" void kernel_launch(void* const* d_in, const int* in_sizes, int n_in,
                              void* d_out, int out_size, void* d_ws, size_t ws_size,
                              hipStream_t stream) {
  (void)in_sizes; (void)n_in; (void)out_size; (void)ws_size;

  float* out = (float*)d_out;
  char* wsb = (char*)d_ws;

  Args a;
  a.meanings  = (const int*)d_in[0];
  a.emb_table = (const float*)d_in[1];
  a.v2e_w     = (const float*)d_in[2];
  a.e2v_w     = (const float*)d_in[3];
  a.e2v_b     = (const float*)d_in[4];
  a.sa_qkv_w  = (const float*)d_in[5];
  a.sa_qkv_b  = (const float*)d_in[6];
  a.sa_out_w  = (const float*)d_in[7];
  a.sa_out_b  = (const float*)d_in[8];
  a.ca_qkv_w  = (const float*)d_in[9];
  a.ca_qkv_b  = (const float*)d_in[10];
  a.ca_out_w  = (const float*)d_in[11];
  a.ca_out_b  = (const float*)d_in[12];
  a.ffn_w1    = (const float*)d_in[13];
  a.ffn_b1    = (const float*)d_in[14];
  a.ffn_w2    = (const float*)d_in[15];
  a.ffn_b2    = (const float*)d_in[16];
  a.ln1_g     = (const float*)d_in[17];
  a.ln1_b     = (const float*)d_in[18];
  a.ln2_g     = (const float*)d_in[19];
  a.ln2_b     = (const float*)d_in[20];
  a.ln3_g     = (const float*)d_in[21];
  a.ln3_b     = (const float*)d_in[22];
  a.outToks   = out;
  a.outLogits = out + Lq * Bn;

  // barrier state: arrive[256] (packed) + gen; zeroed every call
  a.barArrive = (unsigned*)wsb;
  a.barGen    = (unsigned*)(wsb + 1024);
  hipMemsetAsync(wsb, 0, 4096, stream);

  float* ws = (float*)(wsb + 4096);
  a.src    = ws;
  a.tmpv   = a.src    + Bn * Dm;
  a.caC    = a.tmpv   + Bn * Dm;
  a.x      = a.caC    + NL * Bn * Dm;
  a.q      = a.x      + Bn * Dm;
  a.aout   = a.q      + Bn * Dm;
  a.h1     = a.aout   + Bn * Dm;       // doubles as ca scratch in setup
  a.kcache = a.h1     + Bn * DFF;
  a.vcache = a.kcache + (size_t)NL * Lq * Bn * Dm;
  a.partV  = a.vcache + (size_t)NL * Lq * Bn * Dm;
  a.partI  = (int*)(a.partV + (size_t)NGW * 8);

  void* kp[] = { (void*)&a };
  hipLaunchCooperativeKernel((const void*)mega, dim3(NB), dim3(NT), kp, 0, stream);
}